// Round 9
// baseline (218.499 us; speedup 1.0000x reference)
//
#include <hip/hip_runtime.h>

// CrossAttentionGAT — algebraically collapsed; edge path = coarse counting-bin
// (128 buckets of 64 nodes) + LDS-privatized per-bucket segment reduction.
// Round-9: overlap independent stages + shrink dispatch count 8 -> 5:
//   k_binA = bin role (x<128) + a role (x>=128, per-block float4-u ~3us —
//            NOT the r6 shfl-u) in ONE kernel; roles co-resident per CU.
//   k_mo   = memb + out fused, 2 blocks, non-atomic (kills out-memset).
// Dispatches: memset(ws 10KB) + k_binA + k_den + k_waccG + k_mo.
//
// mean(cross1) = mean(emb2) @ Wl + bl   (softmax col-sums == 1)
// mean(cross2) = mean(emb1) @ Wl + bl   (softmax row-sums == 1)
// mean(emb)    = (1/N) * sum_k g[head,k] * W[k, head*C+c] + b
//   g[head,k]  = sum_n w[n,head] x[n,k],  w[n,head] = sum_{e: src=n} alpha_e[head]

#define NN 8192
#define EE 262144
#define NEG 0.2f

#define BKT 128           // node buckets per graph
#define RNG (NN / BKT)    // 64 nodes per bucket
#define CAP 2560          // bucket capacity: mean 2048 + 11 sigma
#define CHK (EE / 128)    // 2048 edges per bin chunk

// ---------------- ws layout (4-byte units) ----------------
#define U_CNT   0                        // 2 graphs x {D,S} x BKT ints (zeroed)
#define U_GACC  (U_CNT + 4*BKT)          // 2*1024 floats (zeroed)
#define U_ZEND  (U_GACC + 2048)
#define U_ASRC  (U_ZEND)                 // 2*NN*8 floats
#define U_ADST  (U_ASRC + 2*NN*8)        // 2*NN*8 floats
#define U_PR    (U_ADST + 2*NN*8)        // 2*NN*16 floats: (adst,rden) float2
#define U_BIND  (U_PR + 2*NN*16)         // 2*BKT*CAP ints
#define U_BINS  (U_BIND + 2*BKT*CAP)     // 2*BKT*CAP ints
#define ZERO_BYTES ((size_t)U_ZEND * 4)

union SMemBA {
  struct { int hD[BKT]; int hS[BKT]; int bD[BKT]; int bS[BKT]; int cD[BKT]; int cS[BKT]; } bin;
  struct { float xs[64][129]; float us[16][128]; } a;   // 41.2 KB
};

// K1: fused bin + a. Grid (256, 2): x<128 bins edge chunk x of graph y;
// x>=128 computes a_src/a_dst for node tile (x-128) of graph y, with u
// recomputed per-block via float4 dots (512KB L2 read, ~3us, overlapped).
__global__ __launch_bounds__(512) void k_binA(
    const int* __restrict__ ei1, const int* __restrict__ ei2,
    const float* __restrict__ x1, const float* __restrict__ W1,
    const float* __restrict__ as1, const float* __restrict__ ad1,
    const float* __restrict__ x2, const float* __restrict__ W2,
    const float* __restrict__ as2, const float* __restrict__ ad2,
    int* __restrict__ cnt, int* __restrict__ binD, int* __restrict__ binS,
    float* __restrict__ asrc, float* __restrict__ adst) {
  __shared__ SMemBA sm;
  int g = blockIdx.y;
  int t = threadIdx.x;

  if (blockIdx.x >= 128) {
    // ---------------- a role: per-block u, then 64-node tile ----------------
    int cb = blockIdx.x - 128;
    const float* Wg = g ? W2 : W1;
    const float* ats = g ? as2 : as1;
    const float* atd = g ? ad2 : ad1;
    // u[sd][head][k]: rows 0..7 = src heads, 8..15 = dst heads. One W chunk
    // read serves both src and dst dots.
    for (int o = t; o < 1024; o += 512) {
      int head = o >> 7, k = o & 127;
      const float4* wr = (const float4*)(Wg + (size_t)k * 1024 + head * 128);
      const float4* asr = (const float4*)(ats + head * 128);
      const float4* adr = (const float4*)(atd + head * 128);
      float ss = 0.f, dd = 0.f;
#pragma unroll 8
      for (int c = 0; c < 32; ++c) {
        float4 w4 = wr[c];
        float4 a4 = asr[c], b4 = adr[c];
        ss += w4.x * a4.x + w4.y * a4.y + w4.z * a4.z + w4.w * a4.w;
        dd += w4.x * b4.x + w4.y * b4.y + w4.z * b4.z + w4.w * b4.w;
      }
      sm.a.us[head][k] = ss;
      sm.a.us[8 + head][k] = dd;
    }
    const float* x = g ? x2 : x1;
    const int n0 = cb * 64;
    const float4* xb4 = (const float4*)(x + (size_t)n0 * 128);
    for (int i = t; i < 64 * 32; i += 512) {
      float4 v = xb4[i];
      int r = i >> 5, c = (i & 31) * 4;
      sm.a.xs[r][c] = v.x; sm.a.xs[r][c + 1] = v.y;
      sm.a.xs[r][c + 2] = v.z; sm.a.xs[r][c + 3] = v.w;
    }
    __syncthreads();
    int nl = t & 63;
    int j0 = (t >> 6) * 2;            // 8 groups x 2 outputs = 16 (8 src + 8 dst)
    float a0 = 0.f, a1 = 0.f;
#pragma unroll 4
    for (int k = 0; k < 128; ++k) {
      float xv = sm.a.xs[nl][k];
      a0 += xv * sm.a.us[j0 + 0][k];
      a1 += xv * sm.a.us[j0 + 1][k];
    }
    int n = n0 + nl;
    float* outp = (j0 < 8) ? (asrc + g * (NN * 8) + n * 8 + j0)
                           : (adst + g * (NN * 8) + n * 8 + (j0 - 8));
    outp[0] = a0; outp[1] = a1;
    return;
  }

  // ---------------- bin role: one 2048-edge chunk -----------------
  const int* ei = g ? ei2 : ei1;
  for (int i = t; i < BKT; i += 512) {
    sm.bin.hD[i] = 0; sm.bin.hS[i] = 0; sm.bin.cD[i] = 0; sm.bin.cS[i] = 0;
  }
  __syncthreads();
  int e0 = blockIdx.x * CHK;
  for (int i = t; i < CHK; i += 512) {
    int s = ei[e0 + i], d = ei[EE + e0 + i];
    atomicAdd(&sm.bin.hD[d >> 6], 1);
    atomicAdd(&sm.bin.hS[s >> 6], 1);
  }
  __syncthreads();
  for (int i = t; i < BKT; i += 512) {
    sm.bin.bD[i] = atomicAdd(cnt + (2 * g + 0) * BKT + i, sm.bin.hD[i]);
    sm.bin.bS[i] = atomicAdd(cnt + (2 * g + 1) * BKT + i, sm.bin.hS[i]);
  }
  __syncthreads();
  int* bdg = binD + (size_t)g * BKT * CAP;
  int* bsg = binS + (size_t)g * BKT * CAP;
  for (int i = t; i < CHK; i += 512) {
    int s = ei[e0 + i], d = ei[EE + e0 + i];
    int kb = d >> 6;
    int p = sm.bin.bD[kb] + atomicAdd(&sm.bin.cD[kb], 1);
    bdg[kb * CAP + p] = (s << 6) | (d & 63);
    kb = s >> 6;
    p = sm.bin.bS[kb] + atomicAdd(&sm.bin.cS[kb], 1);
    bsg[kb * CAP + p] = (d << 6) | (s & 63);
  }
}

// K2: per dst-bucket denominator -> pr = (adst, 1/den)
__global__ __launch_bounds__(512) void k_den(
    const int* __restrict__ cnt, const int* __restrict__ binD,
    const float* __restrict__ asrc, const float* __restrict__ adst,
    float* __restrict__ pr) {
  int gph = blockIdx.y, b = blockIdx.x;
  int lo = b * RNG;
  const float* as = asrc + gph * (NN * 8);
  const float* ad = adst + gph * (NN * 8);
  float2* prg = (float2*)pr + (size_t)gph * (NN * 8);
  __shared__ float den[RNG * 8];
  __shared__ float ads[RNG * 8];
  int t = threadIdx.x;
  for (int i = t; i < RNG * 8; i += 512) {
    float avv = ad[lo * 8 + i];
    float v = as[lo * 8 + i] + avv;      // self loop (s == d)
    v = v > 0.f ? v : NEG * v;
    ads[i] = avv;
    den[i] = __expf(v);
  }
  __syncthreads();
  int n = cnt[(2 * gph + 0) * BKT + b];
  const int* recs = binD + (size_t)gph * BKT * CAP + b * CAP;
  int rid = t >> 3, h = t & 7;
  for (int base = 0; base < n; base += 256) {
    int rv[4]; bool ok[4]; float sv[4];
#pragma unroll
    for (int uu = 0; uu < 4; ++uu) {
      int i = base + uu * 64 + rid;
      ok[uu] = i < n;
      rv[uu] = ok[uu] ? recs[i] : 0;
    }
#pragma unroll
    for (int uu = 0; uu < 4; ++uu)
      sv[uu] = ok[uu] ? as[(rv[uu] >> 6) * 8 + h] : 0.f;
#pragma unroll
    for (int uu = 0; uu < 4; ++uu) {
      if (ok[uu]) {
        int dl = rv[uu] & 63;
        float v = sv[uu] + ads[dl * 8 + h];
        v = v > 0.f ? v : NEG * v;
        atomicAdd(&den[dl * 8 + h], __expf(v));
      }
    }
  }
  __syncthreads();
  for (int i = t; i < RNG * 8; i += 512)
    prg[lo * 8 + i] = make_float2(ads[i], 1.0f / den[i]);
}

// K3: per src-bucket alpha-sum (LDS wv) + fused g-reduce.
__global__ __launch_bounds__(512) void k_waccG(
    const int* __restrict__ cnt, const int* __restrict__ binS,
    const float* __restrict__ asrc, const float* __restrict__ pr,
    const float* __restrict__ x1, const float* __restrict__ x2,
    float* __restrict__ gacc) {
  int gph = blockIdx.y, b = blockIdx.x;
  int lo = b * RNG;
  const float* as = asrc + gph * (NN * 8);
  const float2* prg = (const float2*)pr + (size_t)gph * (NN * 8);
  __shared__ float wv[RNG * 8];
  __shared__ float asx[RNG * 8];
  int t = threadIdx.x;
  for (int i = t; i < RNG * 8; i += 512) {
    float sva = as[lo * 8 + i];
    float2 f2 = prg[lo * 8 + i];         // (adst[n,h], rden[n,h])
    float v = sva + f2.x;                // self loop
    v = v > 0.f ? v : NEG * v;
    asx[i] = sva;
    wv[i] = __expf(v) * f2.y;
  }
  __syncthreads();
  int n = cnt[(2 * gph + 1) * BKT + b];
  const int* recs = binS + (size_t)gph * BKT * CAP + b * CAP;
  int rid = t >> 3, h = t & 7;
  for (int base = 0; base < n; base += 256) {
    int rv[4]; bool ok[4]; float2 pv[4];
#pragma unroll
    for (int uu = 0; uu < 4; ++uu) {
      int i = base + uu * 64 + rid;
      ok[uu] = i < n;
      rv[uu] = ok[uu] ? recs[i] : 0;
    }
#pragma unroll
    for (int uu = 0; uu < 4; ++uu)
      pv[uu] = ok[uu] ? prg[(size_t)(rv[uu] >> 6) * 8 + h] : make_float2(0.f, 0.f);
#pragma unroll
    for (int uu = 0; uu < 4; ++uu) {
      if (ok[uu]) {
        int sl = rv[uu] & 63;
        float v = asx[sl * 8 + h] + pv[uu].x;
        v = v > 0.f ? v : NEG * v;
        atomicAdd(&wv[sl * 8 + h], __expf(v) * pv[uu].y);
      }
    }
  }
  __syncthreads();
  // fused g-reduce: this bucket's 64 nodes, w straight from LDS
  const float* x = gph ? x2 : x1;
  float* gg = gacc + gph * 1024;
  int k = t & 127;
  int h0 = (t >> 7) * 2;               // 4 groups x 2 heads
  int n0 = b * RNG;
  float a0 = 0.f, a1 = 0.f;
#pragma unroll 4
  for (int nl = 0; nl < RNG; ++nl) {
    float xv = x[(size_t)(n0 + nl) * 128 + k];
    a0 += xv * wv[nl * 8 + h0];
    a1 += xv * wv[nl * 8 + h0 + 1];
  }
  atomicAdd(gg + (h0 + 0) * 128 + k, a0);
  atomicAdd(gg + (h0 + 1) * 128 + k, a1);
}

// K4: fused memb + out, 2 blocks, non-atomic. Block b produces out[b*128..+127]
// which needs memb of graph gsel=1-b (out[0..127] uses graph2's memb).
__global__ __launch_bounds__(512) void k_mo(
    const float* __restrict__ gacc,
    const float* __restrict__ W1, const float* __restrict__ b1,
    const float* __restrict__ W2, const float* __restrict__ b2,
    const float* __restrict__ Wl, const float* __restrict__ bl,
    float* __restrict__ out) {
  __shared__ float gl[1024];
  __shared__ float membL[1024];
  __shared__ float po[512];
  int b = blockIdx.x;                  // 0 or 1
  int gsel = 1 - b;
  const float* W = gsel ? W2 : W1;
  const float* bb = gsel ? b2 : b1;
  int t = threadIdx.x;
  for (int i = t; i < 1024; i += 512) gl[i] = gacc[gsel * 1024 + i];
  __syncthreads();
  // memb[e] = (1/N) sum_{k<128} gl[head(e)*128+k] * W[k*1024+e] + bb[e]
  for (int o = t; o < 1024; o += 512) {
    const float* gr = &gl[(o >> 7) * 128];
    float s = 0.f;
#pragma unroll 8
    for (int k = 0; k < 128; ++k) s += gr[k] * W[(size_t)k * 1024 + o];
    membL[o] = s * (1.0f / (float)NN) + bb[o];
  }
  __syncthreads();
  // out[b*128 + j] = sum_{k<1024} membL[k] * Wl[k*128+j] + bl[j]
  {
    int j = t & 127, kc = t >> 7;      // kc = 0..3, 256 k each
    float s = 0.f;
#pragma unroll 8
    for (int k = kc * 256; k < kc * 256 + 256; ++k)
      s += membL[k] * Wl[(size_t)k * 128 + j];
    po[t] = s;
    __syncthreads();
    if (t < 128)
      out[b * 128 + t] = po[t] + po[t + 128] + po[t + 256] + po[t + 384] + bl[t];
  }
}

extern "C" void kernel_launch(void* const* d_in, const int* in_sizes, int n_in,
                              void* d_out, int out_size, void* d_ws, size_t ws_size,
                              hipStream_t stream) {
  const float* x1  = (const float*)d_in[0];
  const int*   ei1 = (const int*)d_in[1];
  const float* W1  = (const float*)d_in[2];
  const float* as1 = (const float*)d_in[3];
  const float* ad1 = (const float*)d_in[4];
  const float* b1  = (const float*)d_in[5];
  const float* x2  = (const float*)d_in[6];
  const int*   ei2 = (const int*)d_in[7];
  const float* W2  = (const float*)d_in[8];
  const float* as2 = (const float*)d_in[9];
  const float* ad2 = (const float*)d_in[10];
  const float* b2  = (const float*)d_in[11];
  const float* Wl  = (const float*)d_in[12];
  const float* bl  = (const float*)d_in[13];
  float* out = (float*)d_out;

  int*   cnt  = (int*)d_ws + U_CNT;
  float* gacc = (float*)d_ws + U_GACC;
  float* asrc = (float*)d_ws + U_ASRC;
  float* adst = (float*)d_ws + U_ADST;
  float* pr   = (float*)d_ws + U_PR;
  int*   binD = (int*)d_ws + U_BIND;
  int*   binS = (int*)d_ws + U_BINS;

  hipMemsetAsync(d_ws, 0, ZERO_BYTES, stream);  // cnt + gacc (10 KB)

  k_binA<<<dim3(256, 2), 512, 0, stream>>>(ei1, ei2, x1, W1, as1, ad1,
                                           x2, W2, as2, ad2,
                                           cnt, binD, binS, asrc, adst);
  k_den<<<dim3(BKT, 2), 512, 0, stream>>>(cnt, binD, asrc, adst, pr);
  k_waccG<<<dim3(BKT, 2), 512, 0, stream>>>(cnt, binS, asrc, pr, x1, x2, gacc);
  k_mo<<<2, 512, 0, stream>>>(gacc, W1, b1, W2, b2, Wl, bl, out);
}

// Round 10
// 183.384 us; speedup vs baseline: 1.1915x; 1.1915x over previous
//
#include <hip/hip_runtime.h>

// CrossAttentionGAT — algebraically collapsed; edge path = coarse counting-bin
// (128 buckets of 64 nodes) + LDS-privatized per-bucket segment reduction.
// Round-10: r8 skeleton (179us proven; r9's two fusions both regressed) plus:
//   k_bin  single-pass: edges + hist-locs in registers (no 2nd ei read, no
//          cD/cS atomics)
//   k_den/k_waccG: unroll 4->8 (deeper load pipelining; they are ~40-55us
//          each per r9 subtraction, latency-bound at 8 waves/CU)
//   k_out  non-atomic 8-block (kills d_out memset dispatch)
// 7 dispatches: memset(ws) + k_bin(+u riders) + k_a + k_den + k_waccG +
// k_memb + k_out.
//
// mean(cross1) = mean(emb2) @ Wl + bl   (softmax col-sums == 1)
// mean(cross2) = mean(emb1) @ Wl + bl   (softmax row-sums == 1)
// mean(emb)    = (1/N) * sum_k g[head,k] * W[k, head*C+c] + b
//   g[head,k]  = sum_n w[n,head] x[n,k],  w[n,head] = sum_{e: src=n} alpha_e[head]

#define NN 8192
#define EE 262144
#define NEG 0.2f

#define BKT 128           // node buckets per graph
#define RNG (NN / BKT)    // 64 nodes per bucket
#define CAP 2560          // bucket capacity: mean 2048 + 11 sigma
#define CHK (EE / 128)    // 2048 edges per bin chunk (= 4 per thread at 512)

// ---------------- ws layout (4-byte units) ----------------
#define U_CNT   0                        // 2 graphs x {D,S} x BKT ints (zeroed)
#define U_GACC  (U_CNT + 4*BKT)          // 2*1024 floats (zeroed)
#define U_ZEND  (U_GACC + 2048)
#define U_U     (U_ZEND)                 // 2*2048 floats: u[g][sd*1024+head*128+k]
#define U_MEMB  (U_U + 2*2048)           // 2*1024 floats (fully written by k_memb)
#define U_ASRC  (U_MEMB + 2048)          // 2*NN*8 floats
#define U_ADST  (U_ASRC + 2*NN*8)        // 2*NN*8 floats
#define U_PR    (U_ADST + 2*NN*8)        // 2*NN*16 floats: (adst,rden) float2
#define U_BIND  (U_PR + 2*NN*16)         // 2*BKT*CAP ints
#define U_BINS  (U_BIND + 2*BKT*CAP)     // 2*BKT*CAP ints
#define ZERO_BYTES ((size_t)U_ZEND * 4)

// K1: bin edges by dst-bucket (payload s<<6|d%64) and src-bucket (d<<6|s%64).
// Single-pass: edges and per-edge histogram offsets kept in registers.
// Rider blocks x=128 (sd=0/src) and x=129 (sd=1/dst) compute u for graph y.
__global__ __launch_bounds__(512) void k_bin(
    const int* __restrict__ ei1, const int* __restrict__ ei2,
    const float* __restrict__ W1, const float* __restrict__ as1,
    const float* __restrict__ ad1,
    const float* __restrict__ W2, const float* __restrict__ as2,
    const float* __restrict__ ad2,
    int* __restrict__ cnt, int* __restrict__ binD, int* __restrict__ binS,
    float* __restrict__ u) {
  int g = blockIdx.y;
  int t = threadIdx.x;
  if (blockIdx.x >= 128) {               // u rider block
    int sd = blockIdx.x - 128;           // 0=src, 1=dst
    const float* Wg = g ? W2 : W1;
    const float* att = g ? (sd ? ad2 : as2) : (sd ? ad1 : as1);
    float* uo = u + g * 2048 + sd * 1024;
    for (int o = t; o < 1024; o += 512) {
      int head = o >> 7, k = o & 127;
      const float4* wr = (const float4*)(Wg + (size_t)k * 1024 + head * 128);
      const float4* ar = (const float4*)(att + head * 128);
      float s = 0.f;
#pragma unroll 8
      for (int c = 0; c < 32; ++c) {
        float4 w4 = wr[c], a4 = ar[c];
        s += w4.x * a4.x + w4.y * a4.y + w4.z * a4.z + w4.w * a4.w;
      }
      uo[o] = s;
    }
    return;
  }
  const int* ei = g ? ei2 : ei1;
  __shared__ int hD[BKT], hS[BKT], bD[BKT], bS[BKT];
  for (int i = t; i < BKT; i += 512) { hD[i] = 0; hS[i] = 0; }
  __syncthreads();
  int e0 = blockIdx.x * CHK;
  int sE[4], dE[4], lD[4], lS[4];
#pragma unroll
  for (int uu = 0; uu < 4; ++uu) {
    int i = e0 + uu * 512 + t;
    sE[uu] = ei[i];
    dE[uu] = ei[EE + i];
  }
#pragma unroll
  for (int uu = 0; uu < 4; ++uu) {
    lD[uu] = atomicAdd(&hD[dE[uu] >> 6], 1);
    lS[uu] = atomicAdd(&hS[sE[uu] >> 6], 1);
  }
  __syncthreads();
  for (int i = t; i < BKT; i += 512) {
    bD[i] = atomicAdd(cnt + (2 * g + 0) * BKT + i, hD[i]);
    bS[i] = atomicAdd(cnt + (2 * g + 1) * BKT + i, hS[i]);
  }
  __syncthreads();
  int* bdg = binD + (size_t)g * BKT * CAP;
  int* bsg = binS + (size_t)g * BKT * CAP;
#pragma unroll
  for (int uu = 0; uu < 4; ++uu) {
    int kb = dE[uu] >> 6;
    bdg[kb * CAP + bD[kb] + lD[uu]] = (sE[uu] << 6) | (dE[uu] & 63);
    kb = sE[uu] >> 6;
    bsg[kb * CAP + bS[kb] + lS[uu]] = (dE[uu] << 6) | (sE[uu] & 63);
  }
}

// K2: a_src[n,h] = x[n,:] . u_src[h,:]; a_dst likewise. 64 nodes/block.
__global__ __launch_bounds__(512) void k_a(
    const float* __restrict__ x1, const float* __restrict__ x2,
    const float* __restrict__ u,
    float* __restrict__ asrc, float* __restrict__ adst) {
  int gph = blockIdx.y, cb = blockIdx.x;
  __shared__ float xs[64][129];
  __shared__ float us[16][128];       // rows 0..7 src heads, 8..15 dst heads
  int t = threadIdx.x;
  const float* ug = u + gph * 2048;
  for (int i = t; i < 2048; i += 512) us[i >> 7][i & 127] = ug[i];
  const float* x = gph ? x2 : x1;
  const int n0 = cb * 64;
  const float4* xb4 = (const float4*)(x + (size_t)n0 * 128);
  for (int i = t; i < 64 * 32; i += 512) {
    float4 v = xb4[i];
    int r = i >> 5, c = (i & 31) * 4;
    xs[r][c] = v.x; xs[r][c + 1] = v.y; xs[r][c + 2] = v.z; xs[r][c + 3] = v.w;
  }
  __syncthreads();
  int nl = t & 63;
  int j0 = (t >> 6) * 2;              // 8 groups x 2 outputs = 16 (8 src + 8 dst)
  float a0 = 0.f, a1 = 0.f;
#pragma unroll 4
  for (int k = 0; k < 128; ++k) {
    float xv = xs[nl][k];
    a0 += xv * us[j0 + 0][k];
    a1 += xv * us[j0 + 1][k];
  }
  int n = n0 + nl;
  float* outp = (j0 < 8) ? (asrc + gph * (NN * 8) + n * 8 + j0)
                         : (adst + gph * (NN * 8) + n * 8 + (j0 - 8));
  outp[0] = a0; outp[1] = a1;
}

// K3: per dst-bucket denominator -> pr = (adst, 1/den). unroll 8.
__global__ __launch_bounds__(512) void k_den(
    const int* __restrict__ cnt, const int* __restrict__ binD,
    const float* __restrict__ asrc, const float* __restrict__ adst,
    float* __restrict__ pr) {
  int gph = blockIdx.y, b = blockIdx.x;
  int lo = b * RNG;
  const float* as = asrc + gph * (NN * 8);
  const float* ad = adst + gph * (NN * 8);
  float2* prg = (float2*)pr + (size_t)gph * (NN * 8);
  __shared__ float den[RNG * 8];
  __shared__ float ads[RNG * 8];
  int t = threadIdx.x;
  for (int i = t; i < RNG * 8; i += 512) {
    float avv = ad[lo * 8 + i];
    float v = as[lo * 8 + i] + avv;      // self loop (s == d)
    v = v > 0.f ? v : NEG * v;
    ads[i] = avv;
    den[i] = __expf(v);
  }
  __syncthreads();
  int n = cnt[(2 * gph + 0) * BKT + b];
  const int* recs = binD + (size_t)gph * BKT * CAP + b * CAP;
  int rid = t >> 3, h = t & 7;
  for (int base = 0; base < n; base += 512) {
    int rv[8]; bool ok[8]; float sv[8];
#pragma unroll
    for (int uu = 0; uu < 8; ++uu) {
      int i = base + uu * 64 + rid;
      ok[uu] = i < n;
      rv[uu] = ok[uu] ? recs[i] : 0;
    }
#pragma unroll
    for (int uu = 0; uu < 8; ++uu)
      sv[uu] = ok[uu] ? as[(rv[uu] >> 6) * 8 + h] : 0.f;
#pragma unroll
    for (int uu = 0; uu < 8; ++uu) {
      if (ok[uu]) {
        int dl = rv[uu] & 63;
        float v = sv[uu] + ads[dl * 8 + h];
        v = v > 0.f ? v : NEG * v;
        atomicAdd(&den[dl * 8 + h], __expf(v));
      }
    }
  }
  __syncthreads();
  for (int i = t; i < RNG * 8; i += 512)
    prg[lo * 8 + i] = make_float2(ads[i], 1.0f / den[i]);
}

// K4: per src-bucket alpha-sum (LDS wv) + fused g-reduce. unroll 8.
__global__ __launch_bounds__(512) void k_waccG(
    const int* __restrict__ cnt, const int* __restrict__ binS,
    const float* __restrict__ asrc, const float* __restrict__ pr,
    const float* __restrict__ x1, const float* __restrict__ x2,
    float* __restrict__ gacc) {
  int gph = blockIdx.y, b = blockIdx.x;
  int lo = b * RNG;
  const float* as = asrc + gph * (NN * 8);
  const float2* prg = (const float2*)pr + (size_t)gph * (NN * 8);
  __shared__ float wv[RNG * 8];
  __shared__ float asx[RNG * 8];
  int t = threadIdx.x;
  for (int i = t; i < RNG * 8; i += 512) {
    float sva = as[lo * 8 + i];
    float2 f2 = prg[lo * 8 + i];         // (adst[n,h], rden[n,h])
    float v = sva + f2.x;                // self loop
    v = v > 0.f ? v : NEG * v;
    asx[i] = sva;
    wv[i] = __expf(v) * f2.y;
  }
  __syncthreads();
  int n = cnt[(2 * gph + 1) * BKT + b];
  const int* recs = binS + (size_t)gph * BKT * CAP + b * CAP;
  int rid = t >> 3, h = t & 7;
  for (int base = 0; base < n; base += 512) {
    int rv[8]; bool ok[8]; float2 pv[8];
#pragma unroll
    for (int uu = 0; uu < 8; ++uu) {
      int i = base + uu * 64 + rid;
      ok[uu] = i < n;
      rv[uu] = ok[uu] ? recs[i] : 0;
    }
#pragma unroll
    for (int uu = 0; uu < 8; ++uu)
      pv[uu] = ok[uu] ? prg[(size_t)(rv[uu] >> 6) * 8 + h] : make_float2(0.f, 0.f);
#pragma unroll
    for (int uu = 0; uu < 8; ++uu) {
      if (ok[uu]) {
        int sl = rv[uu] & 63;
        float v = asx[sl * 8 + h] + pv[uu].x;
        v = v > 0.f ? v : NEG * v;
        atomicAdd(&wv[sl * 8 + h], __expf(v) * pv[uu].y);
      }
    }
  }
  __syncthreads();
  // fused g-reduce: this bucket's 64 nodes, w straight from LDS
  const float* x = gph ? x2 : x1;
  float* gg = gacc + gph * 1024;
  int k = t & 127;
  int h0 = (t >> 7) * 2;               // 4 groups x 2 heads
  int n0 = b * RNG;
  float a0 = 0.f, a1 = 0.f;
#pragma unroll 4
  for (int nl = 0; nl < RNG; ++nl) {
    float xv = x[(size_t)(n0 + nl) * 128 + k];
    a0 += xv * wv[nl * 8 + h0];
    a1 += xv * wv[nl * 8 + h0 + 1];
  }
  atomicAdd(gg + (h0 + 0) * 128 + k, a0);
  atomicAdd(gg + (h0 + 1) * 128 + k, a1);
}

// K5: memb[g][e] = (1/N) sum_{k<128} gacc[g,head(e),k] W[k,e] + b[e].
__global__ __launch_bounds__(512) void k_memb(
    const float* __restrict__ gacc,
    const float* __restrict__ W1, const float* __restrict__ b1,
    const float* __restrict__ W2, const float* __restrict__ b2,
    float* __restrict__ memb) {
  int g = blockIdx.y;
  int e0 = blockIdx.x * 64;
  const float* W = g ? W2 : W1;
  const float* bb = g ? b2 : b1;
  const float* gr = gacc + g * 1024 + (e0 >> 7) * 128;   // head const per block
  __shared__ float pm[8][64];
  int t = threadIdx.x;
  int el = t & 63, kc = t >> 6;        // kc = 0..7
  int e = e0 + el;
  float s = 0.f;
#pragma unroll
  for (int k = kc * 16; k < kc * 16 + 16; ++k)
    s += gr[k] * W[(size_t)k * 1024 + e];
  pm[kc][el] = s;
  __syncthreads();
  if (t < 64) {
    float acc = pm[0][el];
#pragma unroll
    for (int q = 1; q < 8; ++q) acc += pm[q][el];
    memb[g * 1024 + e] = acc * (1.0f / (float)NN) + bb[e];
  }
}

// K6: out = [memb(g2); memb(g1)] @ Wl + bl. 8 blocks x 32 outputs, k split
// 16-way across threads, LDS reduce, non-atomic write (no out memset).
__global__ __launch_bounds__(512) void k_out(
    const float* __restrict__ memb, const float* __restrict__ Wl,
    const float* __restrict__ bl, float* __restrict__ out) {
  __shared__ float ml[1024];
  __shared__ float po[16][32];
  int b = blockIdx.x;                  // 0..7
  int t = threadIdx.x;
  const float* m = (b < 4) ? (memb + 1024) : memb;   // out[0..127] <- graph2
  for (int i = t; i < 1024; i += 512) ml[i] = m[i];
  __syncthreads();
  int ol = t & 31, kc = t >> 5;        // kc = 0..15, 64 k each
  int o = b * 32 + ol;
  int j = o & 127;
  float s = 0.f;
#pragma unroll 8
  for (int k = kc * 64; k < kc * 64 + 64; ++k)
    s += ml[k] * Wl[(size_t)k * 128 + j];
  po[kc][ol] = s;
  __syncthreads();
  if (t < 32) {
    float acc = po[0][t];
#pragma unroll
    for (int q = 1; q < 16; ++q) acc += po[q][t];
    out[b * 32 + t] = acc + bl[(b * 32 + t) & 127];
  }
}

extern "C" void kernel_launch(void* const* d_in, const int* in_sizes, int n_in,
                              void* d_out, int out_size, void* d_ws, size_t ws_size,
                              hipStream_t stream) {
  const float* x1  = (const float*)d_in[0];
  const int*   ei1 = (const int*)d_in[1];
  const float* W1  = (const float*)d_in[2];
  const float* as1 = (const float*)d_in[3];
  const float* ad1 = (const float*)d_in[4];
  const float* b1  = (const float*)d_in[5];
  const float* x2  = (const float*)d_in[6];
  const int*   ei2 = (const int*)d_in[7];
  const float* W2  = (const float*)d_in[8];
  const float* as2 = (const float*)d_in[9];
  const float* ad2 = (const float*)d_in[10];
  const float* b2  = (const float*)d_in[11];
  const float* Wl  = (const float*)d_in[12];
  const float* bl  = (const float*)d_in[13];
  float* out = (float*)d_out;

  int*   cnt  = (int*)d_ws + U_CNT;
  float* gacc = (float*)d_ws + U_GACC;
  float* u    = (float*)d_ws + U_U;
  float* memb = (float*)d_ws + U_MEMB;
  float* asrc = (float*)d_ws + U_ASRC;
  float* adst = (float*)d_ws + U_ADST;
  float* pr   = (float*)d_ws + U_PR;
  int*   binD = (int*)d_ws + U_BIND;
  int*   binS = (int*)d_ws + U_BINS;

  hipMemsetAsync(d_ws, 0, ZERO_BYTES, stream);  // cnt + gacc (10 KB)

  k_bin<<<dim3(130, 2), 512, 0, stream>>>(ei1, ei2, W1, as1, ad1,
                                          W2, as2, ad2, cnt, binD, binS, u);
  k_a<<<dim3(128, 2), 512, 0, stream>>>(x1, x2, u, asrc, adst);
  k_den<<<dim3(BKT, 2), 512, 0, stream>>>(cnt, binD, asrc, adst, pr);
  k_waccG<<<dim3(BKT, 2), 512, 0, stream>>>(cnt, binS, asrc, pr, x1, x2, gacc);
  k_memb<<<dim3(16, 2), 512, 0, stream>>>(gacc, W1, b1, W2, b2, memb);
  k_out<<<8, 512, 0, stream>>>(memb, Wl, bl, out);
}

// Round 11
// 181.340 us; speedup vs baseline: 1.2049x; 1.0113x over previous
//
#include <hip/hip_runtime.h>

// CrossAttentionGAT — algebraically collapsed; edge path = coarse counting-bin
// (128 buckets of 64 nodes) + LDS-privatized per-bucket segment reduction.
// Round-11: 1024-thread blocks on the four big kernels. All were 256-block
// grids = 1 block/CU = 8 waves/CU (Occupancy ~21%), latency-bound (VALU 7-11%,
// HBM <4%). Unroll-8 (r10) was neutral -> ILP isn't binding; wave count is.
// 1024 thr = 16 waves/CU, same grids, same algorithm, half work per thread.
// 7 dispatches: memset(ws) + k_bin(+u riders) + k_a + k_den + k_waccG +
// k_memb + k_out.
//
// mean(cross1) = mean(emb2) @ Wl + bl   (softmax col-sums == 1)
// mean(cross2) = mean(emb1) @ Wl + bl   (softmax row-sums == 1)
// mean(emb)    = (1/N) * sum_k g[head,k] * W[k, head*C+c] + b
//   g[head,k]  = sum_n w[n,head] x[n,k],  w[n,head] = sum_{e: src=n} alpha_e[head]

#define NN 8192
#define EE 262144
#define NEG 0.2f

#define BKT 128           // node buckets per graph
#define RNG (NN / BKT)    // 64 nodes per bucket
#define CAP 2560          // bucket capacity: mean 2048 + 11 sigma
#define CHK (EE / 128)    // 2048 edges per bin chunk (= 2 per thread at 1024)

// ---------------- ws layout (4-byte units) ----------------
#define U_CNT   0                        // 2 graphs x {D,S} x BKT ints (zeroed)
#define U_GACC  (U_CNT + 4*BKT)          // 2*1024 floats (zeroed)
#define U_ZEND  (U_GACC + 2048)
#define U_U     (U_ZEND)                 // 2*2048 floats: u[g][sd*1024+head*128+k]
#define U_MEMB  (U_U + 2*2048)           // 2*1024 floats (fully written by k_memb)
#define U_ASRC  (U_MEMB + 2048)          // 2*NN*8 floats
#define U_ADST  (U_ASRC + 2*NN*8)        // 2*NN*8 floats
#define U_PR    (U_ADST + 2*NN*8)        // 2*NN*16 floats: (adst,rden) float2
#define U_BIND  (U_PR + 2*NN*16)         // 2*BKT*CAP ints
#define U_BINS  (U_BIND + 2*BKT*CAP)     // 2*BKT*CAP ints
#define ZERO_BYTES ((size_t)U_ZEND * 4)

// K1: bin edges by dst-bucket (payload s<<6|d%64) and src-bucket (d<<6|s%64).
// Single-pass: edges and per-edge histogram offsets kept in registers.
// Rider blocks x=128 (sd=0/src) and x=129 (sd=1/dst) compute u for graph y.
__global__ __launch_bounds__(1024) void k_bin(
    const int* __restrict__ ei1, const int* __restrict__ ei2,
    const float* __restrict__ W1, const float* __restrict__ as1,
    const float* __restrict__ ad1,
    const float* __restrict__ W2, const float* __restrict__ as2,
    const float* __restrict__ ad2,
    int* __restrict__ cnt, int* __restrict__ binD, int* __restrict__ binS,
    float* __restrict__ u) {
  int g = blockIdx.y;
  int t = threadIdx.x;
  if (blockIdx.x >= 128) {               // u rider block: 1 output per thread
    int sd = blockIdx.x - 128;           // 0=src, 1=dst
    const float* Wg = g ? W2 : W1;
    const float* att = g ? (sd ? ad2 : as2) : (sd ? ad1 : as1);
    float* uo = u + g * 2048 + sd * 1024;
    int head = t >> 7, k = t & 127;
    const float4* wr = (const float4*)(Wg + (size_t)k * 1024 + head * 128);
    const float4* ar = (const float4*)(att + head * 128);
    float s = 0.f;
#pragma unroll 8
    for (int c = 0; c < 32; ++c) {
      float4 w4 = wr[c], a4 = ar[c];
      s += w4.x * a4.x + w4.y * a4.y + w4.z * a4.z + w4.w * a4.w;
    }
    uo[t] = s;
    return;
  }
  const int* ei = g ? ei2 : ei1;
  __shared__ int hD[BKT], hS[BKT], bD[BKT], bS[BKT];
  if (t < BKT) { hD[t] = 0; hS[t] = 0; }
  __syncthreads();
  int e0 = blockIdx.x * CHK;
  int sE[2], dE[2], lD[2], lS[2];
#pragma unroll
  for (int uu = 0; uu < 2; ++uu) {
    int i = e0 + uu * 1024 + t;
    sE[uu] = ei[i];
    dE[uu] = ei[EE + i];
  }
#pragma unroll
  for (int uu = 0; uu < 2; ++uu) {
    lD[uu] = atomicAdd(&hD[dE[uu] >> 6], 1);
    lS[uu] = atomicAdd(&hS[sE[uu] >> 6], 1);
  }
  __syncthreads();
  if (t < BKT) {
    bD[t] = atomicAdd(cnt + (2 * g + 0) * BKT + t, hD[t]);
    bS[t] = atomicAdd(cnt + (2 * g + 1) * BKT + t, hS[t]);
  }
  __syncthreads();
  int* bdg = binD + (size_t)g * BKT * CAP;
  int* bsg = binS + (size_t)g * BKT * CAP;
#pragma unroll
  for (int uu = 0; uu < 2; ++uu) {
    int kb = dE[uu] >> 6;
    bdg[kb * CAP + bD[kb] + lD[uu]] = (sE[uu] << 6) | (dE[uu] & 63);
    kb = sE[uu] >> 6;
    bsg[kb * CAP + bS[kb] + lS[uu]] = (dE[uu] << 6) | (sE[uu] & 63);
  }
}

// K2: a_src[n,h] = x[n,:] . u_src[h,:]; a_dst likewise. 64 nodes/block,
// 1024 threads: wave w handles output slot j0=w for all 64 nodes.
__global__ __launch_bounds__(1024) void k_a(
    const float* __restrict__ x1, const float* __restrict__ x2,
    const float* __restrict__ u,
    float* __restrict__ asrc, float* __restrict__ adst) {
  int gph = blockIdx.y, cb = blockIdx.x;
  __shared__ float xs[64][129];
  __shared__ float us[16][128];       // rows 0..7 src heads, 8..15 dst heads
  int t = threadIdx.x;
  const float* ug = u + gph * 2048;
  for (int i = t; i < 2048; i += 1024) us[i >> 7][i & 127] = ug[i];
  const float* x = gph ? x2 : x1;
  const int n0 = cb * 64;
  const float4* xb4 = (const float4*)(x + (size_t)n0 * 128);
  for (int i = t; i < 64 * 32; i += 1024) {
    float4 v = xb4[i];
    int r = i >> 5, c = (i & 31) * 4;
    xs[r][c] = v.x; xs[r][c + 1] = v.y; xs[r][c + 2] = v.z; xs[r][c + 3] = v.w;
  }
  __syncthreads();
  int nl = t & 63;
  int j0 = t >> 6;                    // 0..15: wave-uniform output slot
  float a0 = 0.f;
#pragma unroll 4
  for (int k = 0; k < 128; ++k) a0 += xs[nl][k] * us[j0][k];
  int n = n0 + nl;
  if (j0 < 8) asrc[gph * (NN * 8) + n * 8 + j0] = a0;
  else        adst[gph * (NN * 8) + n * 8 + (j0 - 8)] = a0;
}

// K3: per dst-bucket denominator -> pr = (adst, 1/den). 1024 thr, unroll 4.
__global__ __launch_bounds__(1024) void k_den(
    const int* __restrict__ cnt, const int* __restrict__ binD,
    const float* __restrict__ asrc, const float* __restrict__ adst,
    float* __restrict__ pr) {
  int gph = blockIdx.y, b = blockIdx.x;
  int lo = b * RNG;
  const float* as = asrc + gph * (NN * 8);
  const float* ad = adst + gph * (NN * 8);
  float2* prg = (float2*)pr + (size_t)gph * (NN * 8);
  __shared__ float den[RNG * 8];
  __shared__ float ads[RNG * 8];
  int t = threadIdx.x;
  if (t < RNG * 8) {
    float avv = ad[lo * 8 + t];
    float v = as[lo * 8 + t] + avv;      // self loop (s == d)
    v = v > 0.f ? v : NEG * v;
    ads[t] = avv;
    den[t] = __expf(v);
  }
  __syncthreads();
  int n = cnt[(2 * gph + 0) * BKT + b];
  const int* recs = binD + (size_t)gph * BKT * CAP + b * CAP;
  int rid = t >> 3, h = t & 7;           // rid 0..127
  for (int base = 0; base < n; base += 512) {
    int rv[4]; bool ok[4]; float sv[4];
#pragma unroll
    for (int uu = 0; uu < 4; ++uu) {
      int i = base + uu * 128 + rid;
      ok[uu] = i < n;
      rv[uu] = ok[uu] ? recs[i] : 0;
    }
#pragma unroll
    for (int uu = 0; uu < 4; ++uu)
      sv[uu] = ok[uu] ? as[(rv[uu] >> 6) * 8 + h] : 0.f;
#pragma unroll
    for (int uu = 0; uu < 4; ++uu) {
      if (ok[uu]) {
        int dl = rv[uu] & 63;
        float v = sv[uu] + ads[dl * 8 + h];
        v = v > 0.f ? v : NEG * v;
        atomicAdd(&den[dl * 8 + h], __expf(v));
      }
    }
  }
  __syncthreads();
  if (t < RNG * 8)
    prg[lo * 8 + t] = make_float2(ads[t], 1.0f / den[t]);
}

// K4: per src-bucket alpha-sum (LDS wv) + fused g-reduce. 1024 thr.
__global__ __launch_bounds__(1024) void k_waccG(
    const int* __restrict__ cnt, const int* __restrict__ binS,
    const float* __restrict__ asrc, const float* __restrict__ pr,
    const float* __restrict__ x1, const float* __restrict__ x2,
    float* __restrict__ gacc) {
  int gph = blockIdx.y, b = blockIdx.x;
  int lo = b * RNG;
  const float* as = asrc + gph * (NN * 8);
  const float2* prg = (const float2*)pr + (size_t)gph * (NN * 8);
  __shared__ float wv[RNG * 8];
  __shared__ float asx[RNG * 8];
  int t = threadIdx.x;
  if (t < RNG * 8) {
    float sva = as[lo * 8 + t];
    float2 f2 = prg[lo * 8 + t];         // (adst[n,h], rden[n,h])
    float v = sva + f2.x;                // self loop
    v = v > 0.f ? v : NEG * v;
    asx[t] = sva;
    wv[t] = __expf(v) * f2.y;
  }
  __syncthreads();
  int n = cnt[(2 * gph + 1) * BKT + b];
  const int* recs = binS + (size_t)gph * BKT * CAP + b * CAP;
  int rid = t >> 3, h = t & 7;           // rid 0..127
  for (int base = 0; base < n; base += 512) {
    int rv[4]; bool ok[4]; float2 pv[4];
#pragma unroll
    for (int uu = 0; uu < 4; ++uu) {
      int i = base + uu * 128 + rid;
      ok[uu] = i < n;
      rv[uu] = ok[uu] ? recs[i] : 0;
    }
#pragma unroll
    for (int uu = 0; uu < 4; ++uu)
      pv[uu] = ok[uu] ? prg[(size_t)(rv[uu] >> 6) * 8 + h] : make_float2(0.f, 0.f);
#pragma unroll
    for (int uu = 0; uu < 4; ++uu) {
      if (ok[uu]) {
        int sl = rv[uu] & 63;
        float v = asx[sl * 8 + h] + pv[uu].x;
        v = v > 0.f ? v : NEG * v;
        atomicAdd(&wv[sl * 8 + h], __expf(v) * pv[uu].y);
      }
    }
  }
  __syncthreads();
  // fused g-reduce: this bucket's 64 nodes; thread = (h0, k), 1 head each
  const float* x = gph ? x2 : x1;
  float* gg = gacc + gph * 1024;
  int k = t & 127;
  int h0 = t >> 7;                     // 0..7
  int n0 = b * RNG;
  float a0 = 0.f;
#pragma unroll 4
  for (int nl = 0; nl < RNG; ++nl)
    a0 += x[(size_t)(n0 + nl) * 128 + k] * wv[nl * 8 + h0];
  atomicAdd(gg + h0 * 128 + k, a0);
}

// K5: memb[g][e] = (1/N) sum_{k<128} gacc[g,head(e),k] W[k,e] + b[e].
__global__ __launch_bounds__(512) void k_memb(
    const float* __restrict__ gacc,
    const float* __restrict__ W1, const float* __restrict__ b1,
    const float* __restrict__ W2, const float* __restrict__ b2,
    float* __restrict__ memb) {
  int g = blockIdx.y;
  int e0 = blockIdx.x * 64;
  const float* W = g ? W2 : W1;
  const float* bb = g ? b2 : b1;
  const float* gr = gacc + g * 1024 + (e0 >> 7) * 128;   // head const per block
  __shared__ float pm[8][64];
  int t = threadIdx.x;
  int el = t & 63, kc = t >> 6;        // kc = 0..7
  int e = e0 + el;
  float s = 0.f;
#pragma unroll
  for (int k = kc * 16; k < kc * 16 + 16; ++k)
    s += gr[k] * W[(size_t)k * 1024 + e];
  pm[kc][el] = s;
  __syncthreads();
  if (t < 64) {
    float acc = pm[0][el];
#pragma unroll
    for (int q = 1; q < 8; ++q) acc += pm[q][el];
    memb[g * 1024 + e] = acc * (1.0f / (float)NN) + bb[e];
  }
}

// K6: out = [memb(g2); memb(g1)] @ Wl + bl. 8 blocks x 32 outputs, k split
// 16-way across threads, LDS reduce, non-atomic write (no out memset).
__global__ __launch_bounds__(512) void k_out(
    const float* __restrict__ memb, const float* __restrict__ Wl,
    const float* __restrict__ bl, float* __restrict__ out) {
  __shared__ float ml[1024];
  __shared__ float po[16][32];
  int b = blockIdx.x;                  // 0..7
  int t = threadIdx.x;
  const float* m = (b < 4) ? (memb + 1024) : memb;   // out[0..127] <- graph2
  for (int i = t; i < 1024; i += 512) ml[i] = m[i];
  __syncthreads();
  int ol = t & 31, kc = t >> 5;        // kc = 0..15, 64 k each
  int o = b * 32 + ol;
  int j = o & 127;
  float s = 0.f;
#pragma unroll 8
  for (int k = kc * 64; k < kc * 64 + 64; ++k)
    s += ml[k] * Wl[(size_t)k * 128 + j];
  po[kc][ol] = s;
  __syncthreads();
  if (t < 32) {
    float acc = po[0][t];
#pragma unroll
    for (int q = 1; q < 16; ++q) acc += po[q][t];
    out[b * 32 + t] = acc + bl[(b * 32 + t) & 127];
  }
}

extern "C" void kernel_launch(void* const* d_in, const int* in_sizes, int n_in,
                              void* d_out, int out_size, void* d_ws, size_t ws_size,
                              hipStream_t stream) {
  const float* x1  = (const float*)d_in[0];
  const int*   ei1 = (const int*)d_in[1];
  const float* W1  = (const float*)d_in[2];
  const float* as1 = (const float*)d_in[3];
  const float* ad1 = (const float*)d_in[4];
  const float* b1  = (const float*)d_in[5];
  const float* x2  = (const float*)d_in[6];
  const int*   ei2 = (const int*)d_in[7];
  const float* W2  = (const float*)d_in[8];
  const float* as2 = (const float*)d_in[9];
  const float* ad2 = (const float*)d_in[10];
  const float* b2  = (const float*)d_in[11];
  const float* Wl  = (const float*)d_in[12];
  const float* bl  = (const float*)d_in[13];
  float* out = (float*)d_out;

  int*   cnt  = (int*)d_ws + U_CNT;
  float* gacc = (float*)d_ws + U_GACC;
  float* u    = (float*)d_ws + U_U;
  float* memb = (float*)d_ws + U_MEMB;
  float* asrc = (float*)d_ws + U_ASRC;
  float* adst = (float*)d_ws + U_ADST;
  float* pr   = (float*)d_ws + U_PR;
  int*   binD = (int*)d_ws + U_BIND;
  int*   binS = (int*)d_ws + U_BINS;

  hipMemsetAsync(d_ws, 0, ZERO_BYTES, stream);  // cnt + gacc (10 KB)

  k_bin<<<dim3(130, 2), 1024, 0, stream>>>(ei1, ei2, W1, as1, ad1,
                                           W2, as2, ad2, cnt, binD, binS, u);
  k_a<<<dim3(128, 2), 1024, 0, stream>>>(x1, x2, u, asrc, adst);
  k_den<<<dim3(BKT, 2), 1024, 0, stream>>>(cnt, binD, asrc, adst, pr);
  k_waccG<<<dim3(BKT, 2), 1024, 0, stream>>>(cnt, binS, asrc, pr, x1, x2, gacc);
  k_memb<<<dim3(16, 2), 512, 0, stream>>>(gacc, W1, b1, W2, b2, memb);
  k_out<<<8, 512, 0, stream>>>(memb, Wl, bl, out);
}

// Round 12
// 178.126 us; speedup vs baseline: 1.2266x; 1.0180x over previous
//
#include <hip/hip_runtime.h>

// CrossAttentionGAT — algebraically collapsed; edge path = coarse counting-bin
// (128 buckets of 64 nodes) + LDS-privatized per-bucket segment reduction.
// Round-12: overlap the two independent front kernels (r9 retry, done right).
//   k_pre  = zero cnt/gacc + compute u ONCE (replaces ws memset dispatch)
//   k_binA = bin role (x<128, r10 single-pass) ∥ a role (x>=128, r8 body
//            reading PRECOMPUTED global u — 8KB/block, not r9's 512KB
//            per-block W re-read). 512-thr blocks, 2/CU co-resident.
// k_den/k_waccG (1024 thr) and k_memb/k_out byte-identical to r11-verified.
// 6 dispatches: k_pre + k_binA + k_den + k_waccG + k_memb + k_out.
//
// mean(cross1) = mean(emb2) @ Wl + bl   (softmax col-sums == 1)
// mean(cross2) = mean(emb1) @ Wl + bl   (softmax row-sums == 1)
// mean(emb)    = (1/N) * sum_k g[head,k] * W[k, head*C+c] + b
//   g[head,k]  = sum_n w[n,head] x[n,k],  w[n,head] = sum_{e: src=n} alpha_e[head]

#define NN 8192
#define EE 262144
#define NEG 0.2f

#define BKT 128           // node buckets per graph
#define RNG (NN / BKT)    // 64 nodes per bucket
#define CAP 2560          // bucket capacity: mean 2048 + 11 sigma
#define CHK (EE / 128)    // 2048 edges per bin chunk (= 4 per thread at 512)

// ---------------- ws layout (4-byte units) ----------------
#define U_CNT   0                        // 2 graphs x {D,S} x BKT ints (k_pre zeroes)
#define U_GACC  (U_CNT + 4*BKT)          // 2*1024 floats (k_pre zeroes)
#define U_U     (U_GACC + 2048)          // 2*2048 floats: u[g][sd*1024+head*128+k]
#define U_MEMB  (U_U + 2*2048)           // 2*1024 floats (fully written by k_memb)
#define U_ASRC  (U_MEMB + 2048)          // 2*NN*8 floats
#define U_ADST  (U_ASRC + 2*NN*8)        // 2*NN*8 floats
#define U_PR    (U_ADST + 2*NN*8)        // 2*NN*16 floats: (adst,rden) float2
#define U_BIND  (U_PR + 2*NN*16)         // 2*BKT*CAP ints
#define U_BINS  (U_BIND + 2*BKT*CAP)     // 2*BKT*CAP ints

// K0: blk 0 zeroes cnt+gacc; blks 1..4 compute u for (g,sd).
__global__ __launch_bounds__(512) void k_pre(
    const float* __restrict__ W1, const float* __restrict__ as1,
    const float* __restrict__ ad1,
    const float* __restrict__ W2, const float* __restrict__ as2,
    const float* __restrict__ ad2,
    int* __restrict__ cnt, float* __restrict__ gacc, float* __restrict__ u) {
  int t = threadIdx.x;
  if (blockIdx.x == 0) {
    cnt[t] = 0;                         // 4*BKT = 512 ints
#pragma unroll
    for (int i = t; i < 2048; i += 512) gacc[i] = 0.f;
    return;
  }
  int id = blockIdx.x - 1;              // 0..3
  int g = id >> 1, sd = id & 1;
  const float* Wg = g ? W2 : W1;
  const float* att = g ? (sd ? ad2 : as2) : (sd ? ad1 : as1);
  float* uo = u + g * 2048 + sd * 1024;
  for (int o = t; o < 1024; o += 512) {
    int head = o >> 7, k = o & 127;
    const float4* wr = (const float4*)(Wg + (size_t)k * 1024 + head * 128);
    const float4* ar = (const float4*)(att + head * 128);
    float s = 0.f;
#pragma unroll 8
    for (int c = 0; c < 32; ++c) {
      float4 w4 = wr[c], a4 = ar[c];
      s += w4.x * a4.x + w4.y * a4.y + w4.z * a4.z + w4.w * a4.w;
    }
    uo[o] = s;
  }
}

union SMemBA {
  struct { int hD[BKT]; int hS[BKT]; int bD[BKT]; int bS[BKT]; } bin;
  struct { float xs[64][129]; float us[16][128]; } a;   // 41.2 KB
};

// K1: fused bin ∥ a. Grid (256, 2), 512 thr, 2 blocks/CU co-resident.
// x<128: single-pass bin of edge chunk x (r10 body). x>=128: a_src/a_dst for
// node tile (x-128), u staged from global (k_pre output).
__global__ __launch_bounds__(512) void k_binA(
    const int* __restrict__ ei1, const int* __restrict__ ei2,
    const float* __restrict__ x1, const float* __restrict__ x2,
    const float* __restrict__ u,
    int* __restrict__ cnt, int* __restrict__ binD, int* __restrict__ binS,
    float* __restrict__ asrc, float* __restrict__ adst) {
  __shared__ SMemBA sm;
  int g = blockIdx.y;
  int t = threadIdx.x;

  if (blockIdx.x >= 128) {
    // ------------- a role: 64-node tile, u from global -------------
    int cb = blockIdx.x - 128;
    const float* ug = u + g * 2048;
    for (int i = t; i < 2048; i += 512) sm.a.us[i >> 7][i & 127] = ug[i];
    const float* x = g ? x2 : x1;
    const int n0 = cb * 64;
    const float4* xb4 = (const float4*)(x + (size_t)n0 * 128);
    for (int i = t; i < 64 * 32; i += 512) {
      float4 v = xb4[i];
      int r = i >> 5, c = (i & 31) * 4;
      sm.a.xs[r][c] = v.x; sm.a.xs[r][c + 1] = v.y;
      sm.a.xs[r][c + 2] = v.z; sm.a.xs[r][c + 3] = v.w;
    }
    __syncthreads();
    int nl = t & 63;
    int j0 = (t >> 6) * 2;            // 8 groups x 2 outputs = 16 (8 src + 8 dst)
    float a0 = 0.f, a1 = 0.f;
#pragma unroll 4
    for (int k = 0; k < 128; ++k) {
      float xv = sm.a.xs[nl][k];
      a0 += xv * sm.a.us[j0 + 0][k];
      a1 += xv * sm.a.us[j0 + 1][k];
    }
    int n = n0 + nl;
    float* outp = (j0 < 8) ? (asrc + g * (NN * 8) + n * 8 + j0)
                           : (adst + g * (NN * 8) + n * 8 + (j0 - 8));
    outp[0] = a0; outp[1] = a1;
    return;
  }

  // ------------- bin role: single-pass, edges + locs in registers -------------
  const int* ei = g ? ei2 : ei1;
  for (int i = t; i < BKT; i += 512) { sm.bin.hD[i] = 0; sm.bin.hS[i] = 0; }
  __syncthreads();
  int e0 = blockIdx.x * CHK;
  int sE[4], dE[4], lD[4], lS[4];
#pragma unroll
  for (int uu = 0; uu < 4; ++uu) {
    int i = e0 + uu * 512 + t;
    sE[uu] = ei[i];
    dE[uu] = ei[EE + i];
  }
#pragma unroll
  for (int uu = 0; uu < 4; ++uu) {
    lD[uu] = atomicAdd(&sm.bin.hD[dE[uu] >> 6], 1);
    lS[uu] = atomicAdd(&sm.bin.hS[sE[uu] >> 6], 1);
  }
  __syncthreads();
  for (int i = t; i < BKT; i += 512) {
    sm.bin.bD[i] = atomicAdd(cnt + (2 * g + 0) * BKT + i, sm.bin.hD[i]);
    sm.bin.bS[i] = atomicAdd(cnt + (2 * g + 1) * BKT + i, sm.bin.hS[i]);
  }
  __syncthreads();
  int* bdg = binD + (size_t)g * BKT * CAP;
  int* bsg = binS + (size_t)g * BKT * CAP;
#pragma unroll
  for (int uu = 0; uu < 4; ++uu) {
    int kb = dE[uu] >> 6;
    bdg[kb * CAP + sm.bin.bD[kb] + lD[uu]] = (sE[uu] << 6) | (dE[uu] & 63);
    kb = sE[uu] >> 6;
    bsg[kb * CAP + sm.bin.bS[kb] + lS[uu]] = (dE[uu] << 6) | (sE[uu] & 63);
  }
}

// K2: per dst-bucket denominator -> pr = (adst, 1/den). 1024 thr.
__global__ __launch_bounds__(1024) void k_den(
    const int* __restrict__ cnt, const int* __restrict__ binD,
    const float* __restrict__ asrc, const float* __restrict__ adst,
    float* __restrict__ pr) {
  int gph = blockIdx.y, b = blockIdx.x;
  int lo = b * RNG;
  const float* as = asrc + gph * (NN * 8);
  const float* ad = adst + gph * (NN * 8);
  float2* prg = (float2*)pr + (size_t)gph * (NN * 8);
  __shared__ float den[RNG * 8];
  __shared__ float ads[RNG * 8];
  int t = threadIdx.x;
  if (t < RNG * 8) {
    float avv = ad[lo * 8 + t];
    float v = as[lo * 8 + t] + avv;      // self loop (s == d)
    v = v > 0.f ? v : NEG * v;
    ads[t] = avv;
    den[t] = __expf(v);
  }
  __syncthreads();
  int n = cnt[(2 * gph + 0) * BKT + b];
  const int* recs = binD + (size_t)gph * BKT * CAP + b * CAP;
  int rid = t >> 3, h = t & 7;           // rid 0..127
  for (int base = 0; base < n; base += 512) {
    int rv[4]; bool ok[4]; float sv[4];
#pragma unroll
    for (int uu = 0; uu < 4; ++uu) {
      int i = base + uu * 128 + rid;
      ok[uu] = i < n;
      rv[uu] = ok[uu] ? recs[i] : 0;
    }
#pragma unroll
    for (int uu = 0; uu < 4; ++uu)
      sv[uu] = ok[uu] ? as[(rv[uu] >> 6) * 8 + h] : 0.f;
#pragma unroll
    for (int uu = 0; uu < 4; ++uu) {
      if (ok[uu]) {
        int dl = rv[uu] & 63;
        float v = sv[uu] + ads[dl * 8 + h];
        v = v > 0.f ? v : NEG * v;
        atomicAdd(&den[dl * 8 + h], __expf(v));
      }
    }
  }
  __syncthreads();
  if (t < RNG * 8)
    prg[lo * 8 + t] = make_float2(ads[t], 1.0f / den[t]);
}

// K3: per src-bucket alpha-sum (LDS wv) + fused g-reduce. 1024 thr.
__global__ __launch_bounds__(1024) void k_waccG(
    const int* __restrict__ cnt, const int* __restrict__ binS,
    const float* __restrict__ asrc, const float* __restrict__ pr,
    const float* __restrict__ x1, const float* __restrict__ x2,
    float* __restrict__ gacc) {
  int gph = blockIdx.y, b = blockIdx.x;
  int lo = b * RNG;
  const float* as = asrc + gph * (NN * 8);
  const float2* prg = (const float2*)pr + (size_t)gph * (NN * 8);
  __shared__ float wv[RNG * 8];
  __shared__ float asx[RNG * 8];
  int t = threadIdx.x;
  if (t < RNG * 8) {
    float sva = as[lo * 8 + t];
    float2 f2 = prg[lo * 8 + t];         // (adst[n,h], rden[n,h])
    float v = sva + f2.x;                // self loop
    v = v > 0.f ? v : NEG * v;
    asx[t] = sva;
    wv[t] = __expf(v) * f2.y;
  }
  __syncthreads();
  int n = cnt[(2 * gph + 1) * BKT + b];
  const int* recs = binS + (size_t)gph * BKT * CAP + b * CAP;
  int rid = t >> 3, h = t & 7;           // rid 0..127
  for (int base = 0; base < n; base += 512) {
    int rv[4]; bool ok[4]; float2 pv[4];
#pragma unroll
    for (int uu = 0; uu < 4; ++uu) {
      int i = base + uu * 128 + rid;
      ok[uu] = i < n;
      rv[uu] = ok[uu] ? recs[i] : 0;
    }
#pragma unroll
    for (int uu = 0; uu < 4; ++uu)
      pv[uu] = ok[uu] ? prg[(size_t)(rv[uu] >> 6) * 8 + h] : make_float2(0.f, 0.f);
#pragma unroll
    for (int uu = 0; uu < 4; ++uu) {
      if (ok[uu]) {
        int sl = rv[uu] & 63;
        float v = asx[sl * 8 + h] + pv[uu].x;
        v = v > 0.f ? v : NEG * v;
        atomicAdd(&wv[sl * 8 + h], __expf(v) * pv[uu].y);
      }
    }
  }
  __syncthreads();
  // fused g-reduce: this bucket's 64 nodes; thread = (h0, k), 1 head each
  const float* x = gph ? x2 : x1;
  float* gg = gacc + gph * 1024;
  int k = t & 127;
  int h0 = t >> 7;                     // 0..7
  int n0 = b * RNG;
  float a0 = 0.f;
#pragma unroll 4
  for (int nl = 0; nl < RNG; ++nl)
    a0 += x[(size_t)(n0 + nl) * 128 + k] * wv[nl * 8 + h0];
  atomicAdd(gg + h0 * 128 + k, a0);
}

// K4: memb[g][e] = (1/N) sum_{k<128} gacc[g,head(e),k] W[k,e] + b[e].
__global__ __launch_bounds__(512) void k_memb(
    const float* __restrict__ gacc,
    const float* __restrict__ W1, const float* __restrict__ b1,
    const float* __restrict__ W2, const float* __restrict__ b2,
    float* __restrict__ memb) {
  int g = blockIdx.y;
  int e0 = blockIdx.x * 64;
  const float* W = g ? W2 : W1;
  const float* bb = g ? b2 : b1;
  const float* gr = gacc + g * 1024 + (e0 >> 7) * 128;   // head const per block
  __shared__ float pm[8][64];
  int t = threadIdx.x;
  int el = t & 63, kc = t >> 6;        // kc = 0..7
  int e = e0 + el;
  float s = 0.f;
#pragma unroll
  for (int k = kc * 16; k < kc * 16 + 16; ++k)
    s += gr[k] * W[(size_t)k * 1024 + e];
  pm[kc][el] = s;
  __syncthreads();
  if (t < 64) {
    float acc = pm[0][el];
#pragma unroll
    for (int q = 1; q < 8; ++q) acc += pm[q][el];
    memb[g * 1024 + e] = acc * (1.0f / (float)NN) + bb[e];
  }
}

// K5: out = [memb(g2); memb(g1)] @ Wl + bl. 8 blocks x 32 outputs, non-atomic.
__global__ __launch_bounds__(512) void k_out(
    const float* __restrict__ memb, const float* __restrict__ Wl,
    const float* __restrict__ bl, float* __restrict__ out) {
  __shared__ float ml[1024];
  __shared__ float po[16][32];
  int b = blockIdx.x;                  // 0..7
  int t = threadIdx.x;
  const float* m = (b < 4) ? (memb + 1024) : memb;   // out[0..127] <- graph2
  for (int i = t; i < 1024; i += 512) ml[i] = m[i];
  __syncthreads();
  int ol = t & 31, kc = t >> 5;        // kc = 0..15, 64 k each
  int o = b * 32 + ol;
  int j = o & 127;
  float s = 0.f;
#pragma unroll 8
  for (int k = kc * 64; k < kc * 64 + 64; ++k)
    s += ml[k] * Wl[(size_t)k * 128 + j];
  po[kc][ol] = s;
  __syncthreads();
  if (t < 32) {
    float acc = po[0][t];
#pragma unroll
    for (int q = 1; q < 16; ++q) acc += po[q][t];
    out[b * 32 + t] = acc + bl[(b * 32 + t) & 127];
  }
}

extern "C" void kernel_launch(void* const* d_in, const int* in_sizes, int n_in,
                              void* d_out, int out_size, void* d_ws, size_t ws_size,
                              hipStream_t stream) {
  const float* x1  = (const float*)d_in[0];
  const int*   ei1 = (const int*)d_in[1];
  const float* W1  = (const float*)d_in[2];
  const float* as1 = (const float*)d_in[3];
  const float* ad1 = (const float*)d_in[4];
  const float* b1  = (const float*)d_in[5];
  const float* x2  = (const float*)d_in[6];
  const int*   ei2 = (const int*)d_in[7];
  const float* W2  = (const float*)d_in[8];
  const float* as2 = (const float*)d_in[9];
  const float* ad2 = (const float*)d_in[10];
  const float* b2  = (const float*)d_in[11];
  const float* Wl  = (const float*)d_in[12];
  const float* bl  = (const float*)d_in[13];
  float* out = (float*)d_out;

  int*   cnt  = (int*)d_ws + U_CNT;
  float* gacc = (float*)d_ws + U_GACC;
  float* u    = (float*)d_ws + U_U;
  float* memb = (float*)d_ws + U_MEMB;
  float* asrc = (float*)d_ws + U_ASRC;
  float* adst = (float*)d_ws + U_ADST;
  float* pr   = (float*)d_ws + U_PR;
  int*   binD = (int*)d_ws + U_BIND;
  int*   binS = (int*)d_ws + U_BINS;

  k_pre<<<5, 512, 0, stream>>>(W1, as1, ad1, W2, as2, ad2, cnt, gacc, u);
  k_binA<<<dim3(256, 2), 512, 0, stream>>>(ei1, ei2, x1, x2, u,
                                           cnt, binD, binS, asrc, adst);
  k_den<<<dim3(BKT, 2), 1024, 0, stream>>>(cnt, binD, asrc, adst, pr);
  k_waccG<<<dim3(BKT, 2), 1024, 0, stream>>>(cnt, binS, asrc, pr, x1, x2, gacc);
  k_memb<<<dim3(16, 2), 512, 0, stream>>>(gacc, W1, b1, W2, b2, memb);
  k_out<<<8, 512, 0, stream>>>(memb, Wl, bl, out);
}